// Round 1
// baseline (1169.087 us; speedup 1.0000x reference)
//
#include <hip/hip_runtime.h>
#include <hip/hip_bf16.h>

// ---------- helpers ----------

__device__ __forceinline__ unsigned short f2bf(float f) {
    // round-to-nearest-even fp32 -> bf16 (no NaN inputs here)
    unsigned u = __float_as_uint(f);
    unsigned r = (u + 0x7fffu + ((u >> 16) & 1u)) >> 16;
    return (unsigned short)r;
}

__device__ __forceinline__ float quant1(float v) {
    // bit_ste: clamp [-1,1], round(|v|*255)/255 (round-half-even), restore sign
    float a = fminf(fabsf(v), 1.0f);
    return copysignf(rintf(a * 255.0f) * (1.0f / 255.0f), v);
}

__device__ __forceinline__ void load_lds16(const void* g, void* l) {
    // global -> LDS direct DMA, 16B per lane; LDS dest = wave-uniform base + lane*16
    __builtin_amdgcn_global_load_lds(
        (const __attribute__((address_space(1))) void*)g,
        (__attribute__((address_space(3))) void*)l,
        16, 0, 0);
}

// ---------- conversion kernels ----------

__global__ void cvt_x_kernel(const float4* __restrict__ x, ushort4* __restrict__ o, int n4) {
    int i = blockIdx.x * blockDim.x + threadIdx.x;
    if (i >= n4) return;
    float4 v = x[i];
    ushort4 r;
    r.x = f2bf(v.x); r.y = f2bf(v.y); r.z = f2bf(v.z); r.w = f2bf(v.w);
    o[i] = r;
}

__global__ void quant_w_kernel(const float4* __restrict__ w, ushort4* __restrict__ o, int n4) {
    int i = blockIdx.x * blockDim.x + threadIdx.x;
    if (i >= n4) return;
    float4 v = w[i];
    ushort4 r;
    r.x = f2bf(quant1(v.x)); r.y = f2bf(quant1(v.y));
    r.z = f2bf(quant1(v.z)); r.w = f2bf(quant1(v.w));
    o[i] = r;
}

// ---------- bf16 MFMA GEMM: C[M,N] = A[M,K] * W[N,K]^T + bit_ste(bias) ----------

#define BM 128
#define BN 128
#define BK 32

typedef __attribute__((ext_vector_type(8))) short bf16x8;
typedef __attribute__((ext_vector_type(4))) float f32x4;

__global__ __launch_bounds__(256) void gemm_bt(
    const unsigned short* __restrict__ A,   // [M][K] bf16 bits
    const unsigned short* __restrict__ Bw,  // [N][K] bf16 bits (already B^T layout)
    const float* __restrict__ bias,         // [N] fp32 (quantized in epilogue)
    float* __restrict__ C,                  // [M][N] fp32
    int M, int N, int K)
{
    __shared__ unsigned short lds_a[BM * BK];  // [m][k], k contiguous, 8 KB
    __shared__ unsigned short lds_b[BN * BK];  // [n][k], k contiguous, 8 KB

    const int tid  = threadIdx.x;
    const int wave = tid >> 6;
    const int lane = tid & 63;
    const int wm = wave >> 1;      // wave row (0..1) -> 64 rows
    const int wn = wave & 1;       // wave col (0..1) -> 64 cols

    const int tileM = blockIdx.y * BM;
    const int tileN = blockIdx.x * BN;

    // staging: 8 chunks of 1024B per 8KB tile; wave w stages chunks 2w, 2w+1
    const int ch0  = wave * 2;
    const int lrow = lane >> 2;          // row within 16-row chunk
    const int lk   = (lane & 3) * 8;     // k element offset (0,8,16,24)

    const unsigned short* ga0 = A  + (size_t)(tileM + ch0 * 16 + lrow) * K + lk;
    const unsigned short* ga1 = ga0 + (size_t)16 * K;
    const unsigned short* gb0 = Bw + (size_t)(tileN + ch0 * 16 + lrow) * K + lk;
    const unsigned short* gb1 = gb0 + (size_t)16 * K;

    unsigned short* la0 = &lds_a[ch0 * 512];
    unsigned short* la1 = &lds_a[ch0 * 512 + 512];
    unsigned short* lb0 = &lds_b[ch0 * 512];
    unsigned short* lb1 = &lds_b[ch0 * 512 + 512];

    f32x4 acc[4][4];
#pragma unroll
    for (int i = 0; i < 4; i++)
#pragma unroll
        for (int j = 0; j < 4; j++) acc[i][j] = (f32x4){0.f, 0.f, 0.f, 0.f};

    // fragment read coords: A-operand layout m=lane&15, k=(lane>>4)*8+j
    const int arow = wm * 64 + (lane & 15);
    const int brow = wn * 64 + (lane & 15);
    const int kfr  = (lane >> 4) * 8;

    for (int k0 = 0; k0 < K; k0 += BK) {
        __syncthreads();   // previous iter's LDS reads complete before overwrite
        load_lds16(ga0, la0);
        load_lds16(ga1, la1);
        load_lds16(gb0, lb0);
        load_lds16(gb1, lb1);
        ga0 += BK; ga1 += BK; gb0 += BK; gb1 += BK;
        __syncthreads();   // staging (vmcnt) drained before fragment reads

        bf16x8 af[4], bfr[4];
#pragma unroll
        for (int t = 0; t < 4; t++) {
            af[t]  = *(const bf16x8*)&lds_a[(arow + t * 16) * BK + kfr];
            bfr[t] = *(const bf16x8*)&lds_b[(brow + t * 16) * BK + kfr];
        }
#pragma unroll
        for (int i = 0; i < 4; i++)
#pragma unroll
            for (int j = 0; j < 4; j++)
                acc[i][j] = __builtin_amdgcn_mfma_f32_16x16x32_bf16(
                    af[i], bfr[j], acc[i][j], 0, 0, 0);
    }

    // epilogue: C/D layout col=lane&15, row=(lane>>4)*4+reg
    const int col0  = lane & 15;
    const int rquad = (lane >> 4) * 4;
#pragma unroll
    for (int j = 0; j < 4; j++) {
        int gn = tileN + wn * 64 + j * 16 + col0;
        float b  = bias[gn];
        float qb = quant1(b);
#pragma unroll
        for (int i = 0; i < 4; i++) {
            int gm = tileM + wm * 64 + i * 16 + rquad;
#pragma unroll
            for (int r = 0; r < 4; r++) {
                C[(size_t)(gm + r) * N + gn] = acc[i][j][r] + qb;
            }
        }
    }
}

// ---------- slow-but-correct fallback (only if ws too small) ----------

__global__ void gemm_fallback(const float* __restrict__ x, const float* __restrict__ w,
                              const float* __restrict__ bias, float* __restrict__ out,
                              int M, int N, int K)
{
    int idx = blockIdx.x * 256 + threadIdx.x;
    if (idx >= M * N) return;
    int m = idx / N, n = idx - m * N;
    const float* xr = x + (size_t)m * K;
    const float* wr = w + (size_t)n * K;
    float s = 0.f;
    for (int k = 0; k < K; k++) s += xr[k] * quant1(wr[k]);
    out[idx] = s + quant1(bias[n]);
}

// ---------- launch ----------

extern "C" void kernel_launch(void* const* d_in, const int* in_sizes, int n_in,
                              void* d_out, int out_size, void* d_ws, size_t ws_size,
                              hipStream_t stream) {
    const float* x    = (const float*)d_in[0];
    const float* w    = (const float*)d_in[1];
    const float* bias = (const float*)d_in[2];
    float* out = (float*)d_out;

    const int N = in_sizes[2];           // 4096
    const int K = in_sizes[1] / N;       // 4096
    const int M = in_sizes[0] / K;       // 16384

    size_t qw_bytes = (size_t)N * K * 2;
    size_t xb_bytes = (size_t)M * K * 2;

    if (ws_size >= qw_bytes + xb_bytes && (M % BM) == 0 && (N % BN) == 0 && (K % BK) == 0) {
        unsigned short* qw = (unsigned short*)d_ws;
        unsigned short* xb = (unsigned short*)((char*)d_ws + qw_bytes);

        int nw4 = (N * K) / 4;
        quant_w_kernel<<<(nw4 + 255) / 256, 256, 0, stream>>>(
            (const float4*)w, (ushort4*)qw, nw4);

        int nx4 = (M * K) / 4;
        cvt_x_kernel<<<(nx4 + 255) / 256, 256, 0, stream>>>(
            (const float4*)x, (ushort4*)xb, nx4);

        dim3 grid(N / BN, M / BM);
        gemm_bt<<<grid, 256, 0, stream>>>(xb, qw, bias, out, M, N, K);
    } else {
        int total = M * N;
        gemm_fallback<<<(total + 255) / 256, 256, 0, stream>>>(x, w, bias, out, M, N, K);
    }
}

// Round 2
// 1155.805 us; speedup vs baseline: 1.0115x; 1.0115x over previous
//
#include <hip/hip_runtime.h>
#include <hip/hip_bf16.h>

// ---------- helpers ----------

__device__ __forceinline__ unsigned short f2bf(float f) {
    // round-to-nearest-even fp32 -> bf16 (no NaN inputs here)
    unsigned u = __float_as_uint(f);
    unsigned r = (u + 0x7fffu + ((u >> 16) & 1u)) >> 16;
    return (unsigned short)r;
}

__device__ __forceinline__ float quant1(float v) {
    // bit_ste: clamp [-1,1], round(|v|*255)/255 (round-half-even), restore sign
    float a = fminf(fabsf(v), 1.0f);
    return copysignf(rintf(a * 255.0f) * (1.0f / 255.0f), v);
}

__device__ __forceinline__ void load_lds16(const void* g, void* l) {
    // global -> LDS direct DMA, 16B per lane; LDS dest = wave-uniform base + lane*16
    __builtin_amdgcn_global_load_lds(
        (const __attribute__((address_space(1))) void*)g,
        (__attribute__((address_space(3))) void*)l,
        16, 0, 0);
}

typedef __attribute__((ext_vector_type(8))) unsigned short u16x8;

// ---------- conversion kernels (8 elem/thread, 16B stores) ----------

__global__ void cvt_x_kernel(const float4* __restrict__ x, u16x8* __restrict__ o, int n8) {
    int i = blockIdx.x * blockDim.x + threadIdx.x;
    if (i >= n8) return;
    float4 a = x[2 * i], b = x[2 * i + 1];
    u16x8 r;
    r[0] = f2bf(a.x); r[1] = f2bf(a.y); r[2] = f2bf(a.z); r[3] = f2bf(a.w);
    r[4] = f2bf(b.x); r[5] = f2bf(b.y); r[6] = f2bf(b.z); r[7] = f2bf(b.w);
    o[i] = r;
}

__global__ void quant_w_kernel(const float4* __restrict__ w, u16x8* __restrict__ o, int n8) {
    int i = blockIdx.x * blockDim.x + threadIdx.x;
    if (i >= n8) return;
    float4 a = w[2 * i], b = w[2 * i + 1];
    u16x8 r;
    r[0] = f2bf(quant1(a.x)); r[1] = f2bf(quant1(a.y));
    r[2] = f2bf(quant1(a.z)); r[3] = f2bf(quant1(a.w));
    r[4] = f2bf(quant1(b.x)); r[5] = f2bf(quant1(b.y));
    r[6] = f2bf(quant1(b.z)); r[7] = f2bf(quant1(b.w));
    o[i] = r;
}

// ---------- bf16 MFMA GEMM: C[M,N] = A[M,K] * W[N,K]^T + bit_ste(bias) ----------
//
// LDS bank-conflict swizzle: physical LDS slot is forced by global_load_lds
// (lane -> base + lane*16). We permute which logical k-chunk each lane FETCHES:
//   c_log = c_phys ^ ((row>>1)&3)
// so fragment reads at physical chunk (q ^ ((row>>1)&3)) land each 4-bank group
// on exactly 2 lanes per quarter-wave (2-way = free, m136), vs 8-way before.

#define BM 128
#define BN 128
#define BK 32

typedef __attribute__((ext_vector_type(8))) short bf16x8;
typedef __attribute__((ext_vector_type(4))) float f32x4;

__global__ __launch_bounds__(256) void gemm_bt(
    const unsigned short* __restrict__ A,   // [M][K] bf16 bits
    const unsigned short* __restrict__ Bw,  // [N][K] bf16 bits (already B^T layout)
    const float* __restrict__ bias,         // [N] fp32 (quantized in epilogue)
    float* __restrict__ C,                  // [M][N] fp32
    int M, int N, int K)
{
    __shared__ unsigned short lds_a[BM * BK];  // [m][k-swizzled], 8 KB
    __shared__ unsigned short lds_b[BN * BK];  // [n][k-swizzled], 8 KB

    const int tid  = threadIdx.x;
    const int wave = tid >> 6;
    const int lane = tid & 63;
    const int wm = wave >> 1;      // wave row (0..1) -> 64 rows
    const int wn = wave & 1;       // wave col (0..1) -> 64 cols

    const int tileM = blockIdx.y * BM;
    const int tileN = blockIdx.x * BN;

    // staging: 8 chunks of 1024B (16 rows) per 8KB tile; wave w stages chunks 2w, 2w+1
    const int ch0  = wave * 2;
    const int lrow = lane >> 2;                               // row within 16-row chunk
    const int lk   = (((lane & 3) ^ ((lrow >> 1) & 3)) * 8);  // swizzled k-chunk fetch

    const unsigned short* ga0 = A  + (size_t)(tileM + ch0 * 16 + lrow) * K + lk;
    const unsigned short* ga1 = ga0 + (size_t)16 * K;
    const unsigned short* gb0 = Bw + (size_t)(tileN + ch0 * 16 + lrow) * K + lk;
    const unsigned short* gb1 = gb0 + (size_t)16 * K;

    unsigned short* la0 = &lds_a[ch0 * 512];
    unsigned short* la1 = &lds_a[ch0 * 512 + 512];
    unsigned short* lb0 = &lds_b[ch0 * 512];
    unsigned short* lb1 = &lds_b[ch0 * 512 + 512];

    f32x4 acc[4][4];
#pragma unroll
    for (int i = 0; i < 4; i++)
#pragma unroll
        for (int j = 0; j < 4; j++) acc[i][j] = (f32x4){0.f, 0.f, 0.f, 0.f};

    // fragment read coords: A-operand layout m=lane&15, k=(lane>>4)*8+j
    // physical k-chunk = logical q XOR swizzle(row); row bits 1-2 == lane bits 1-2
    const int arow = wm * 64 + (lane & 15);
    const int brow = wn * 64 + (lane & 15);
    const int kfr  = (((lane >> 4) ^ ((lane >> 1) & 3)) * 8);

    for (int k0 = 0; k0 < K; k0 += BK) {
        __syncthreads();   // previous iter's LDS reads complete before overwrite
        load_lds16(ga0, la0);
        load_lds16(ga1, la1);
        load_lds16(gb0, lb0);
        load_lds16(gb1, lb1);
        ga0 += BK; ga1 += BK; gb0 += BK; gb1 += BK;
        __syncthreads();   // staging (vmcnt) drained before fragment reads

        bf16x8 af[4], bfr[4];
#pragma unroll
        for (int t = 0; t < 4; t++) {
            af[t]  = *(const bf16x8*)&lds_a[(arow + t * 16) * BK + kfr];
            bfr[t] = *(const bf16x8*)&lds_b[(brow + t * 16) * BK + kfr];
        }
#pragma unroll
        for (int i = 0; i < 4; i++)
#pragma unroll
            for (int j = 0; j < 4; j++)
                acc[i][j] = __builtin_amdgcn_mfma_f32_16x16x32_bf16(
                    af[i], bfr[j], acc[i][j], 0, 0, 0);
    }

    // epilogue: C/D layout col=lane&15, row=(lane>>4)*4+reg
    const int col0  = lane & 15;
    const int rquad = (lane >> 4) * 4;
#pragma unroll
    for (int j = 0; j < 4; j++) {
        int gn = tileN + wn * 64 + j * 16 + col0;
        float b  = bias[gn];
        float qb = quant1(b);
#pragma unroll
        for (int i = 0; i < 4; i++) {
            int gm = tileM + wm * 64 + i * 16 + rquad;
#pragma unroll
            for (int r = 0; r < 4; r++) {
                C[(size_t)(gm + r) * N + gn] = acc[i][j][r] + qb;
            }
        }
    }
}

// ---------- slow-but-correct fallback (only if ws too small) ----------

__global__ void gemm_fallback(const float* __restrict__ x, const float* __restrict__ w,
                              const float* __restrict__ bias, float* __restrict__ out,
                              int M, int N, int K)
{
    int idx = blockIdx.x * 256 + threadIdx.x;
    if (idx >= M * N) return;
    int m = idx / N, n = idx - m * N;
    const float* xr = x + (size_t)m * K;
    const float* wr = w + (size_t)n * K;
    float s = 0.f;
    for (int k = 0; k < K; k++) s += xr[k] * quant1(wr[k]);
    out[idx] = s + quant1(bias[n]);
}

// ---------- launch ----------

extern "C" void kernel_launch(void* const* d_in, const int* in_sizes, int n_in,
                              void* d_out, int out_size, void* d_ws, size_t ws_size,
                              hipStream_t stream) {
    const float* x    = (const float*)d_in[0];
    const float* w    = (const float*)d_in[1];
    const float* bias = (const float*)d_in[2];
    float* out = (float*)d_out;

    const int N = in_sizes[2];           // 4096
    const int K = in_sizes[1] / N;       // 4096
    const int M = in_sizes[0] / K;       // 16384

    size_t qw_bytes = (size_t)N * K * 2;
    size_t xb_bytes = (size_t)M * K * 2;

    if (ws_size >= qw_bytes + xb_bytes && (M % BM) == 0 && (N % BN) == 0 && (K % BK) == 0) {
        unsigned short* qw = (unsigned short*)d_ws;
        unsigned short* xb = (unsigned short*)((char*)d_ws + qw_bytes);

        int nw8 = (N * K) / 8;
        quant_w_kernel<<<(nw8 + 255) / 256, 256, 0, stream>>>(
            (const float4*)w, (u16x8*)qw, nw8);

        int nx8 = (M * K) / 8;
        cvt_x_kernel<<<(nx8 + 255) / 256, 256, 0, stream>>>(
            (const float4*)x, (u16x8*)xb, nx8);

        dim3 grid(N / BN, M / BM);
        gemm_bt<<<grid, 256, 0, stream>>>(xb, qw, bias, out, M, N, K);
    } else {
        int total = M * N;
        gemm_fallback<<<(total + 255) / 256, 256, 0, stream>>>(x, w, bias, out, M, N, K);
    }
}